// Round 12
// baseline (852.881 us; speedup 1.0000x reference)
//
#include <hip/hip_runtime.h>
#include <hip/hip_cooperative_groups.h>

namespace cg = cooperative_groups;

#define T_ 512
#define N_ 60
#define F_ 2
#define C_ 64
#define H_ 512
#define IN_ 3840
#define FOURH 2048
#define PRED_SZ 61440
#define ADJ_SZ 1843200
#define K2_ 128    // padded reduced-K for the Wih2 GEMM (120 real + 8 zero)
#define LDSK 40    // padded LDS row stride in bf16 units (2-way conflicts only)
#define HSLOT 262144   // one h slot (512*512 bf16)

typedef __attribute__((ext_vector_type(8))) short bf8;
typedef __attribute__((ext_vector_type(4))) float f4;

__device__ __forceinline__ unsigned short f2bf(float f)
{
    unsigned int u = __float_as_uint(f);
    u = (u + 0x7FFFu + ((u >> 16) & 1u)) >> 16;
    return (unsigned short)u;
}

// merged weight casts + state init + frame-0 copy (one launch, segment ladder)
__global__ void prep_init_k(const float* Whh, const float* W1, const float* W2,
                            const float* W3, const float* W4, const float* feat,
                            unsigned short* Whh_bf, unsigned short* W1_bf,
                            unsigned short* W2_bf, unsigned short* W3_bf,
                            unsigned short* W4_bf,
                            unsigned short* hAll, float* c, float* out)
{
    long i = (long)blockIdx.x * 256 + threadIdx.x;   // 10496 blocks = 2,686,976
    if (i < 1048576) { Whh_bf[i] = f2bf(Whh[i]); return; }
    i -= 1048576;
    if (i < 262144) { W1_bf[i] = f2bf(W1[i]); return; }
    i -= 262144;
    if (i < 526336) { W2_bf[i] = f2bf(W2[i]); return; }
    i -= 526336;
    if (i < 526336) { W3_bf[i] = f2bf(W3[i]); return; }
    i -= 526336;
    if (i < 61440) { W4_bf[i] = f2bf(W4[i]); return; }
    i -= 61440;
    hAll[i] = 0;
    c[i] = 0.0f;
    if (i < PRED_SZ) out[i] = feat[i];
}

// ---------------------------------------------------------------------------
// Wih2[o, n*2+f] = sum_c Wih[o, n*64+c] * W[f,c]; biasAll = bih+bhh+Wih@b
// ---------------------------------------------------------------------------
__global__ __launch_bounds__(256) void wih2_k(
    const float* Wih, const float* W, const float* b,
    const float* bih, const float* bhh,
    unsigned short* Wih2_bf, float* biasAll)
{
    __shared__ float row[IN_];
    __shared__ float wc[2][64];
    __shared__ float bb[64];
    __shared__ float red[256];

    int o = blockIdx.x;
    int tid = threadIdx.x;

    if (tid < 128) wc[tid >> 6][tid & 63] = W[tid];
    if (tid < 64) bb[tid] = b[tid];
    for (int k = tid; k < IN_; k += 256) row[k] = Wih[(long)o * IN_ + k];
    __syncthreads();

    if (tid < 128) {
        float s = 0.0f;
        if (tid < 120) {
            int n = tid >> 1;
            int f = tid & 1;
            for (int c2 = 0; c2 < 64; ++c2) s += row[n * 64 + c2] * wc[f][c2];
        }
        Wih2_bf[(long)o * K2_ + tid] = f2bf(s);
    }

    float sb = 0.0f;
    for (int k = tid; k < IN_; k += 256) sb += row[k] * bb[k & 63];
    red[tid] = sb;
    __syncthreads();
    for (int s = 128; s > 0; s >>= 1) {
        if (tid < s) red[tid] += red[tid + s];
        __syncthreads();
    }
    if (tid == 0) biasAll[o] = bih[o] + bhh[o] + red[0];
}

// ---------------------------------------------------------------------------
// Encoder GCN (reduced): blockIdx.x = frame*512 + t ; 128 threads.
// ---------------------------------------------------------------------------
__global__ __launch_bounds__(128) void gcn_enc_y(
    const float* x, const float* adj, unsigned short* Y)
{
    __shared__ float sA[N_][N_];
    __shared__ float sx[N_][2];
    __shared__ float snorm[N_];

    int frame = blockIdx.x >> 9;
    int t = blockIdx.x & 511;
    const float* xf = x + (long)frame * PRED_SZ + (long)t * 120;
    const float* af = adj + (long)frame * ADJ_SZ + (long)t * 3600;
    int tid = threadIdx.x;

    for (int l = tid; l < N_ * N_; l += 128) {
        int i = l / N_;
        int j = l - i * N_;
        float a = af[l];
        if (i == j) a += 1.0f;
        sA[i][j] = a;
    }
    if (tid < 120) sx[tid >> 1][tid & 1] = xf[tid];
    __syncthreads();

    if (tid < N_) {
        float d = 0.0f;
        for (int j = 0; j < N_; ++j) d += sA[tid][j];
        snorm[tid] = (d > 0.0f) ? rsqrtf(d) : 0.0f;
    }
    __syncthreads();

    if (tid < 128) {
        float y = 0.0f;
        if (tid < 120) {
            int n = tid >> 1;
            int f = tid & 1;
            float s = 0.0f;
            for (int j = 0; j < N_; ++j) s += sA[n][j] * snorm[j] * sx[j][f];
            y = snorm[n] * s;
        }
        Y[(long)blockIdx.x * K2_ + tid] = f2bf(y);
    }
}

// ---------------------------------------------------------------------------
// Decoder GCN (standalone, fallback path)
// ---------------------------------------------------------------------------
__global__ __launch_bounds__(128) void gcn_dec_y(
    const float* pred, const float* stdv, const float* meanv, unsigned short* Y)
{
    __shared__ float sA[N_][N_];
    __shared__ float sx[N_][2];
    __shared__ float dx0[N_];
    __shared__ float dx1[N_];
    __shared__ int sex[N_];
    __shared__ float snorm[N_];

    int t = blockIdx.x;
    int tid = threadIdx.x;
    const float* pr = pred + (long)t * 120;

    if (tid < 120) sx[tid >> 1][tid & 1] = pr[tid];
    if (tid < N_) {
        float vx = pr[tid * 2 + 0] * stdv[0] + meanv[0];
        float vy = pr[tid * 2 + 1] * stdv[1] + meanv[1];
        dx0[tid] = vx;
        dx1[tid] = vy;
        sex[tid] = (vx > 0.04f) && (vy > 0.04f);
    }
    __syncthreads();

    for (int l = tid; l < N_ * N_; l += 128) {
        int i = l / N_;
        int j = l - i * N_;
        float ddx = dx0[i] - dx0[j];
        float ddy = dx1[i] - dx1[j];
        float d = sqrtf(ddx * ddx + ddy * ddy);
        int conn = ((d > 0.0f) && (d < 10.0f)) || (i == j);
        float a = (sex[i] && sex[j] && conn) ? 1.0f : 0.0f;
        if (i == j) a += 1.0f;
        sA[i][j] = a;
    }
    __syncthreads();

    if (tid < N_) {
        float d = 0.0f;
        for (int j = 0; j < N_; ++j) d += sA[tid][j];
        snorm[tid] = (d > 0.0f) ? rsqrtf(d) : 0.0f;
    }
    __syncthreads();

    if (tid < 128) {
        float y = 0.0f;
        if (tid < 120) {
            int n = tid >> 1;
            int f = tid & 1;
            float s = 0.0f;
            for (int j = 0; j < N_; ++j) s += sA[n][j] * snorm[j] * sx[j][f];
            y = snorm[n] * s;
        }
        Y[(long)t * K2_ + tid] = f2bf(y);
    }
}

// ---------------------------------------------------------------------------
// 32x32-tile MFMA GEMM, B stored [K][Nc]; dbuf LDS + 2-deep prefetch.
// mode 2: Cbf = bf16(relu(acc+b)); mode 3: Cf = acc+b.  (standalone)
// ---------------------------------------------------------------------------
__global__ __launch_bounds__(256) void mlp_gemm(
    const unsigned short* Abf, const unsigned short* Bb,
    const float* bias1, float* Cf, unsigned short* Cbf,
    int M, int Nc, int K, int mode)
{
    __shared__ unsigned short As[2][32 * LDSK];
    __shared__ unsigned short Bs[2][32 * LDSK];

    int tid = threadIdx.x;
    int wave = tid >> 6;
    int wt = wave >> 1, wj = wave & 1;
    int lane = tid & 63;
    int quad = lane >> 4;
    int l16 = lane & 15;
    int row0 = blockIdx.y * 32;
    int col0 = blockIdx.x * 32;

    f4 acc = {0.f, 0.f, 0.f, 0.f};
    const ushort4 zu = make_ushort4(0, 0, 0, 0);
    int sr = tid >> 3;
    int sko = (tid & 7) * 4;

    auto loadA = [&](int k0, ushort4& v) {
        int gm = row0 + sr, gk = k0 + sko;
        v = zu;
        if (gm < M && gk + 4 <= K) v = *(const ushort4*)&Abf[(long)gm * K + gk];
    };
    auto loadB = [&](int k0, ushort4& v) {
        int gk = k0 + sr;
        int gn0 = col0 + sko;
        v = zu;
        if (gk < K) {
            if (gn0 + 4 <= Nc) {
                v = *(const ushort4*)&Bb[(long)gk * Nc + gn0];
            } else {
                unsigned short tmp[4] = {0, 0, 0, 0};
                for (int i = 0; i < 4; ++i)
                    if (gn0 + i < Nc) tmp[i] = Bb[(long)gk * Nc + gn0 + i];
                v = make_ushort4(tmp[0], tmp[1], tmp[2], tmp[3]);
            }
        }
    };

    int niter = (K + 31) / 32;
    ushort4 a0, b0, a1 = zu, b1 = zu, a2 = zu, b2 = zu;
    loadA(0, a0);
    loadB(0, b0);
    if (niter > 1) { loadA(32, a1); loadB(32, b1); }

    for (int it = 0; it < niter; ++it) {
        if (it + 2 < niter) {
            loadA((it + 2) * 32, a2);
            loadB((it + 2) * 32, b2);
        }
        int bf = it & 1;
        *(ushort4*)&As[bf][sr * LDSK + sko] = a0;
        Bs[bf][(sko + 0) * LDSK + sr] = b0.x;
        Bs[bf][(sko + 1) * LDSK + sr] = b0.y;
        Bs[bf][(sko + 2) * LDSK + sr] = b0.z;
        Bs[bf][(sko + 3) * LDSK + sr] = b0.w;
        __syncthreads();

        bf8 fa = *(const bf8*)&As[bf][(wt * 16 + l16) * LDSK + quad * 8];
        bf8 fb = *(const bf8*)&Bs[bf][(wj * 16 + l16) * LDSK + quad * 8];
        acc = __builtin_amdgcn_mfma_f32_16x16x32_bf16(fa, fb, acc, 0, 0, 0);

        a0 = a1; a1 = a2; b0 = b1; b1 = b2;
    }

    int gn = col0 + wj * 16 + l16;
    if (gn < Nc) {
        float bsv = bias1[gn];
        #pragma unroll
        for (int r = 0; r < 4; ++r) {
            int gm = row0 + wt * 16 + quad * 4 + r;
            if (gm >= M) continue;
            float v = acc[r] + bsv;
            long idx = (long)gm * Nc + gn;
            if (mode == 2) {
                if (v < 0.0f) v = 0.0f;
                Cbf[idx] = f2bf(v);
            } else {
                Cf[idx] = v;
            }
        }
    }
}

// ---------------------------------------------------------------------------
// Batched W1 over h slots {1,2,3,4,7}: M = 2560 rows, A-row indirection.
// ---------------------------------------------------------------------------
__global__ __launch_bounds__(256) void mlp_w1b(
    const unsigned short* hAll, const unsigned short* Bb,
    const float* bias1, unsigned short* Cbf)
{
    __shared__ unsigned short As[2][32 * LDSK];
    __shared__ unsigned short Bs[2][32 * LDSK];

    int tid = threadIdx.x;
    int wave = tid >> 6;
    int wt = wave >> 1, wj = wave & 1;
    int lane = tid & 63;
    int quad = lane >> 4;
    int l16 = lane & 15;
    int row0 = blockIdx.y * 32;
    int col0 = blockIdx.x * 32;

    f4 acc = {0.f, 0.f, 0.f, 0.f};
    int sr = tid >> 3;
    int sko = (tid & 7) * 4;

    int gr = row0 + sr;
    int sidx = gr >> 9;
    int slot = (sidx < 4) ? (sidx + 1) : 7;
    const unsigned short* arow = hAll + (long)slot * HSLOT + (long)(gr & 511) * H_;

    auto loadA = [&](int k0, ushort4& v) {
        v = *(const ushort4*)&arow[k0 + sko];
    };
    auto loadB = [&](int k0, ushort4& v) {
        v = *(const ushort4*)&Bb[(long)(k0 + sr) * 512 + col0 + sko];
    };

    ushort4 a0, b0, a1, b1, a2 = make_ushort4(0,0,0,0), b2 = a2;
    loadA(0, a0); loadB(0, b0);
    loadA(32, a1); loadB(32, b1);

    for (int it = 0; it < 16; ++it) {
        if (it + 2 < 16) { loadA((it + 2) * 32, a2); loadB((it + 2) * 32, b2); }
        int bf = it & 1;
        *(ushort4*)&As[bf][sr * LDSK + sko] = a0;
        Bs[bf][(sko + 0) * LDSK + sr] = b0.x;
        Bs[bf][(sko + 1) * LDSK + sr] = b0.y;
        Bs[bf][(sko + 2) * LDSK + sr] = b0.z;
        Bs[bf][(sko + 3) * LDSK + sr] = b0.w;
        __syncthreads();

        bf8 fa = *(const bf8*)&As[bf][(wt * 16 + l16) * LDSK + quad * 8];
        bf8 fb = *(const bf8*)&Bs[bf][(wj * 16 + l16) * LDSK + quad * 8];
        acc = __builtin_amdgcn_mfma_f32_16x16x32_bf16(fa, fb, acc, 0, 0, 0);

        a0 = a1; a1 = a2; b0 = b1; b1 = b2;
    }

    int gn = col0 + wj * 16 + l16;
    float bsv = bias1[gn];
    #pragma unroll
    for (int r = 0; r < 4; ++r) {
        int gm = row0 + wt * 16 + quad * 4 + r;
        float v = acc[r] + bsv;
        if (v < 0.0f) v = 0.0f;
        Cbf[(long)gm * 512 + gn] = f2bf(v);
    }
}

// ---------------------------------------------------------------------------
// Batched W4: A = m3 (2560 x 512), Nc=120; row -> out frame {1,2,3,4,7}.
// ---------------------------------------------------------------------------
__global__ __launch_bounds__(256) void mlp_w4b(
    const unsigned short* Abf, const unsigned short* Bb,
    const float* bias1, float* out)
{
    __shared__ unsigned short As[2][32 * LDSK];
    __shared__ unsigned short Bs[2][32 * LDSK];

    int tid = threadIdx.x;
    int wave = tid >> 6;
    int wt = wave >> 1, wj = wave & 1;
    int lane = tid & 63;
    int quad = lane >> 4;
    int l16 = lane & 15;
    int row0 = blockIdx.y * 32;
    int col0 = blockIdx.x * 32;

    f4 acc = {0.f, 0.f, 0.f, 0.f};
    const ushort4 zu = make_ushort4(0, 0, 0, 0);
    int sr = tid >> 3;
    int sko = (tid & 7) * 4;

    auto loadA = [&](int k0, ushort4& v) {
        v = *(const ushort4*)&Abf[(long)(row0 + sr) * 512 + k0 + sko];
    };
    auto loadB = [&](int k0, ushort4& v) {
        int gn0 = col0 + sko;
        v = zu;
        if (gn0 + 4 <= 120) {
            v = *(const ushort4*)&Bb[(long)(k0 + sr) * 120 + gn0];
        } else {
            unsigned short tmp[4] = {0, 0, 0, 0};
            for (int i = 0; i < 4; ++i)
                if (gn0 + i < 120) tmp[i] = Bb[(long)(k0 + sr) * 120 + gn0 + i];
            v = make_ushort4(tmp[0], tmp[1], tmp[2], tmp[3]);
        }
    };

    ushort4 a0, b0, a1, b1, a2 = zu, b2 = zu;
    loadA(0, a0); loadB(0, b0);
    loadA(32, a1); loadB(32, b1);

    for (int it = 0; it < 16; ++it) {
        if (it + 2 < 16) { loadA((it + 2) * 32, a2); loadB((it + 2) * 32, b2); }
        int bf = it & 1;
        *(ushort4*)&As[bf][sr * LDSK + sko] = a0;
        Bs[bf][(sko + 0) * LDSK + sr] = b0.x;
        Bs[bf][(sko + 1) * LDSK + sr] = b0.y;
        Bs[bf][(sko + 2) * LDSK + sr] = b0.z;
        Bs[bf][(sko + 3) * LDSK + sr] = b0.w;
        __syncthreads();

        bf8 fa = *(const bf8*)&As[bf][(wt * 16 + l16) * LDSK + quad * 8];
        bf8 fb = *(const bf8*)&Bs[bf][(wj * 16 + l16) * LDSK + quad * 8];
        acc = __builtin_amdgcn_mfma_f32_16x16x32_bf16(fa, fb, acc, 0, 0, 0);

        a0 = a1; a1 = a2; b0 = b1; b1 = b2;
    }

    int gn = col0 + wj * 16 + l16;
    if (gn < 120) {
        float bsv = bias1[gn];
        #pragma unroll
        for (int r = 0; r < 4; ++r) {
            int gm = row0 + wt * 16 + quad * 4 + r;
            int sidx = gm >> 9;
            int frame = (sidx < 4) ? (sidx + 1) : 7;
            out[(long)frame * PRED_SZ + (long)(gm & 511) * 120 + gn] = acc[r] + bsv;
        }
    }
}

// ---------------------------------------------------------------------------
// Fused gates + LSTM (standalone, fallback path). niter=20 (Y 4 + h 16).
// ---------------------------------------------------------------------------
__global__ __launch_bounds__(256) void whh_lstm_k(
    const unsigned short* hprev, const unsigned short* Whh_bf,
    const unsigned short* Yf, const unsigned short* Wih2_bf,
    const float* biasAll, float* c, unsigned short* hnew)
{
    __shared__ unsigned short As[2][32 * LDSK];
    __shared__ unsigned short Bs[2][128 * LDSK];

    int tid = threadIdx.x;
    int wave = tid >> 6;
    int wt = wave >> 1, wj = wave & 1;
    int lane = tid & 63;
    int quad = lane >> 4;
    int l16 = lane & 15;
    int j0 = blockIdx.x * 32;
    int row0 = blockIdx.y * 32;

    int sr = tid >> 3;
    int sko = (tid & 7) * 4;
    int br = tid >> 1;
    int bko = (tid & 1) * 16;
    long brow = (long)((br >> 5) * H_ + j0 + (br & 31));
    long bb_w = brow * H_;
    long bb_y = brow * K2_;
    long ar_h = (long)(row0 + sr) * H_;
    long ar_y = (long)(row0 + sr) * K2_;

    f4 acc[4];
    #pragma unroll
    for (int g = 0; g < 4; ++g) acc[g] = f4{0.f, 0.f, 0.f, 0.f};

    auto loadT = [&](int it, ushort4& a, uint4& q0, uint4& q1) {
        if (it < 4) {
            int k = it * 32;
            a  = *(const ushort4*)&Yf[ar_y + k + sko];
            q0 = *(const uint4*)&Wih2_bf[bb_y + k + bko];
            q1 = *(const uint4*)&Wih2_bf[bb_y + k + bko + 8];
        } else {
            int k = (it - 4) * 32;
            a  = *(const ushort4*)&hprev[ar_h + k + sko];
            q0 = *(const uint4*)&Whh_bf[bb_w + k + bko];
            q1 = *(const uint4*)&Whh_bf[bb_w + k + bko + 8];
        }
    };

    ushort4 a0, a1, a2 = make_ushort4(0, 0, 0, 0);
    uint4 q00, q01, q10, q11, q20 = uint4{0,0,0,0}, q21 = uint4{0,0,0,0};
    loadT(0, a0, q00, q01);
    loadT(1, a1, q10, q11);

    for (int it = 0; it < 20; ++it) {
        if (it + 2 < 20) loadT(it + 2, a2, q20, q21);
        int bf = it & 1;
        *(ushort4*)&As[bf][sr * LDSK + sko] = a0;
        *(uint4*)&Bs[bf][br * LDSK + bko]     = q00;
        *(uint4*)&Bs[bf][br * LDSK + bko + 8] = q01;
        __syncthreads();

        bf8 fa = *(const bf8*)&As[bf][(wt * 16 + l16) * LDSK + quad * 8];
        #pragma unroll
        for (int g = 0; g < 4; ++g) {
            bf8 fb = *(const bf8*)&Bs[bf][(g * 32 + wj * 16 + l16) * LDSK + quad * 8];
            acc[g] = __builtin_amdgcn_mfma_f32_16x16x32_bf16(fa, fb, acc[g], 0, 0, 0);
        }

        a0 = a1; a1 = a2;
        q00 = q10; q01 = q11; q10 = q20; q11 = q21;
    }

    int j = j0 + wj * 16 + l16;
    float b_i = biasAll[j];
    float b_f = biasAll[512 + j];
    float b_g = biasAll[1024 + j];
    float b_o = biasAll[1536 + j];
    #pragma unroll
    for (int r = 0; r < 4; ++r) {
        int t = row0 + wt * 16 + quad * 4 + r;
        float gi = acc[0][r] + b_i;
        float gf = acc[1][r] + b_f;
        float gg = acc[2][r] + b_g;
        float go = acc[3][r] + b_o;
        float ig = 1.0f / (1.0f + expf(-gi));
        float fg = 1.0f / (1.0f + expf(-gf));
        float g2 = tanhf(gg);
        float og = 1.0f / (1.0f + expf(-go));
        long ci = (long)t * H_ + j;
        float cn = fg * c[ci] + ig * g2;
        c[ci] = cn;
        hnew[ci] = f2bf(og * tanhf(cn));
    }
}

// ===========================================================================
// Cooperative spine kernel: 5 encoder whh steps + 2 decoder tails, all in
// one launch with grid.sync() between phases. 256 blocks x 256 threads
// (1 block/CU -> co-resident). Shared-memory union 31,744 B.
// ===========================================================================

// --- phase: fused gates+LSTM (same math as whh_lstm_k; niter selectable) ---
__device__ __forceinline__ void whh_phase(
    unsigned char* smem, int tid, int blk,
    const unsigned short* hprev, const unsigned short* Whh_bf,
    const unsigned short* Yf, const unsigned short* Wih2_bf,
    const float* biasAll, float* c, unsigned short* hnew, int withH)
{
    unsigned short* AsB = (unsigned short*)smem;            // 2 x 1280
    unsigned short* BsB = (unsigned short*)(smem + 5120);   // 2 x 5120

    int wave = tid >> 6;
    int wt = wave >> 1, wj = wave & 1;
    int lane = tid & 63;
    int quad = lane >> 4;
    int l16 = lane & 15;
    int j0 = (blk & 15) * 32;
    int row0 = (blk >> 4) * 32;

    int sr = tid >> 3;
    int sko = (tid & 7) * 4;
    int br = tid >> 1;
    int bko = (tid & 1) * 16;
    long brow = (long)((br >> 5) * H_ + j0 + (br & 31));
    long bb_w = brow * H_;
    long bb_y = brow * K2_;
    long ar_h = (long)(row0 + sr) * H_;
    long ar_y = (long)(row0 + sr) * K2_;

    f4 acc[4];
    #pragma unroll
    for (int g = 0; g < 4; ++g) acc[g] = f4{0.f, 0.f, 0.f, 0.f};

    int niter = withH ? 20 : 4;   // step 0: h == 0, skip h-part (adds exact 0)

    auto loadT = [&](int it, ushort4& a, uint4& q0, uint4& q1) {
        if (it < 4) {
            int k = it * 32;
            a  = *(const ushort4*)&Yf[ar_y + k + sko];
            q0 = *(const uint4*)&Wih2_bf[bb_y + k + bko];
            q1 = *(const uint4*)&Wih2_bf[bb_y + k + bko + 8];
        } else {
            int k = (it - 4) * 32;
            a  = *(const ushort4*)&hprev[ar_h + k + sko];
            q0 = *(const uint4*)&Whh_bf[bb_w + k + bko];
            q1 = *(const uint4*)&Whh_bf[bb_w + k + bko + 8];
        }
    };

    ushort4 a0, a1, a2 = make_ushort4(0, 0, 0, 0);
    uint4 q00, q01, q10, q11, q20 = uint4{0,0,0,0}, q21 = uint4{0,0,0,0};
    loadT(0, a0, q00, q01);
    loadT(1, a1, q10, q11);

    for (int it = 0; it < niter; ++it) {
        if (it + 2 < niter) loadT(it + 2, a2, q20, q21);
        int bf = it & 1;
        *(ushort4*)&AsB[bf * 1280 + sr * LDSK + sko] = a0;
        *(uint4*)&BsB[bf * 5120 + br * LDSK + bko]     = q00;
        *(uint4*)&BsB[bf * 5120 + br * LDSK + bko + 8] = q01;
        __syncthreads();

        bf8 fa = *(const bf8*)&AsB[bf * 1280 + (wt * 16 + l16) * LDSK + quad * 8];
        #pragma unroll
        for (int g = 0; g < 4; ++g) {
            bf8 fb = *(const bf8*)&BsB[bf * 5120 + (g * 32 + wj * 16 + l16) * LDSK + quad * 8];
            acc[g] = __builtin_amdgcn_mfma_f32_16x16x32_bf16(fa, fb, acc[g], 0, 0, 0);
        }

        a0 = a1; a1 = a2;
        q00 = q10; q01 = q11; q10 = q20; q11 = q21;
    }

    int j = j0 + wj * 16 + l16;
    float b_i = biasAll[j];
    float b_f = biasAll[512 + j];
    float b_g = biasAll[1024 + j];
    float b_o = biasAll[1536 + j];
    #pragma unroll
    for (int r = 0; r < 4; ++r) {
        int t = row0 + wt * 16 + quad * 4 + r;
        float gi = acc[0][r] + b_i;
        float gf = acc[1][r] + b_f;
        float gg = acc[2][r] + b_g;
        float go = acc[3][r] + b_o;
        float ig = 1.0f / (1.0f + expf(-gi));
        float fg = 1.0f / (1.0f + expf(-gf));
        float g2 = tanhf(gg);
        float og = 1.0f / (1.0f + expf(-go));
        long ci = (long)t * H_ + j;
        float cn = fg * c[ci] + ig * g2;
        c[ci] = cn;
        hnew[ci] = f2bf(og * tanhf(cn));
    }
}

// --- phase: one MLP layer as grid-strided 32x32 tiles (same math) ---
__device__ __forceinline__ void mlp_phase(
    unsigned char* smem, int tid, int blk, int nblk,
    const unsigned short* Abf, const unsigned short* Bb,
    const float* bias1, float* Cf, unsigned short* Cbf,
    int M, int Nc, int K, int mode)
{
    unsigned short* AsB = (unsigned short*)smem;            // 2 x 1280
    unsigned short* BsB = (unsigned short*)(smem + 5120);   // 2 x 1280

    int wave = tid >> 6;
    int wt = wave >> 1, wj = wave & 1;
    int lane = tid & 63;
    int quad = lane >> 4;
    int l16 = lane & 15;
    int sr = tid >> 3;
    int sko = (tid & 7) * 4;
    const ushort4 zu = make_ushort4(0, 0, 0, 0);

    int ntx = (Nc + 31) >> 5;
    int NT = ntx * ((M + 31) >> 5);
    int niter = (K + 31) / 32;

    for (int tile = blk; tile < NT; tile += nblk) {
        int col0 = (tile % ntx) * 32;
        int row0 = (tile / ntx) * 32;

        f4 acc = {0.f, 0.f, 0.f, 0.f};

        auto loadA = [&](int k0, ushort4& v) {
            int gm = row0 + sr, gk = k0 + sko;
            v = zu;
            if (gm < M && gk + 4 <= K) v = *(const ushort4*)&Abf[(long)gm * K + gk];
        };
        auto loadB = [&](int k0, ushort4& v) {
            int gk = k0 + sr;
            int gn0 = col0 + sko;
            v = zu;
            if (gk < K) {
                if (gn0 + 4 <= Nc) {
                    v = *(const ushort4*)&Bb[(long)gk * Nc + gn0];
                } else {
                    unsigned short tmp[4] = {0, 0, 0, 0};
                    for (int i = 0; i < 4; ++i)
                        if (gn0 + i < Nc) tmp[i] = Bb[(long)gk * Nc + gn0 + i];
                    v = make_ushort4(tmp[0], tmp[1], tmp[2], tmp[3]);
                }
            }
        };

        ushort4 a0, b0, a1 = zu, b1 = zu, a2 = zu, b2 = zu;
        loadA(0, a0);
        loadB(0, b0);
        if (niter > 1) { loadA(32, a1); loadB(32, b1); }

        for (int it = 0; it < niter; ++it) {
            if (it + 2 < niter) {
                loadA((it + 2) * 32, a2);
                loadB((it + 2) * 32, b2);
            }
            int bf = it & 1;
            *(ushort4*)&AsB[bf * 1280 + sr * LDSK + sko] = a0;
            BsB[bf * 1280 + (sko + 0) * LDSK + sr] = b0.x;
            BsB[bf * 1280 + (sko + 1) * LDSK + sr] = b0.y;
            BsB[bf * 1280 + (sko + 2) * LDSK + sr] = b0.z;
            BsB[bf * 1280 + (sko + 3) * LDSK + sr] = b0.w;
            __syncthreads();

            bf8 fa = *(const bf8*)&AsB[bf * 1280 + (wt * 16 + l16) * LDSK + quad * 8];
            bf8 fb = *(const bf8*)&BsB[bf * 1280 + (wj * 16 + l16) * LDSK + quad * 8];
            acc = __builtin_amdgcn_mfma_f32_16x16x32_bf16(fa, fb, acc, 0, 0, 0);

            a0 = a1; a1 = a2; b0 = b1; b1 = b2;
        }

        int gn = col0 + wj * 16 + l16;
        if (gn < Nc) {
            float bsv = bias1[gn];
            #pragma unroll
            for (int r = 0; r < 4; ++r) {
                int gm = row0 + wt * 16 + quad * 4 + r;
                if (gm >= M) continue;
                float v = acc[r] + bsv;
                long idx = (long)gm * Nc + gn;
                if (mode == 2) {
                    if (v < 0.0f) v = 0.0f;
                    Cbf[idx] = f2bf(v);
                } else {
                    Cf[idx] = v;
                }
            }
        }
        __syncthreads();   // protect LDS reuse across tiles
    }
}

// --- phase: decoder GCN; 2 trajectories per block (128-thread halves) ---
__device__ __forceinline__ void gcn_phase(
    unsigned char* smem, int tid, int blk,
    const float* pred, const float* stdv, const float* meanv,
    unsigned short* Y)
{
    int half = tid >> 7;
    int lt = tid & 127;
    int t = blk * 2 + half;

    float* sA    = (float*)(smem + half * 15872);   // 3600 f
    float* sx    = sA + 3600;                       // 120 f  (flat [n*2+f])
    float* dx0   = sx + 120;                        // 60 f
    float* dx1   = dx0 + 60;                        // 60 f
    int*   sex   = (int*)(dx1 + 60);                // 60 i
    float* snorm = (float*)(sex + 60);              // 60 f

    const float* pr = pred + (long)t * 120;

    if (lt < 120) sx[lt] = pr[lt];
    if (lt < N_) {
        float vx = pr[lt * 2 + 0] * stdv[0] + meanv[0];
        float vy = pr[lt * 2 + 1] * stdv[1] + meanv[1];
        dx0[lt] = vx;
        dx1[lt] = vy;
        sex[lt] = (vx > 0.04f) && (vy > 0.04f);
    }
    __syncthreads();

    for (int l = lt; l < N_ * N_; l += 128) {
        int i = l / N_;
        int j = l - i * N_;
        float ddx = dx0[i] - dx0[j];
        float ddy = dx1[i] - dx1[j];
        float d = sqrtf(ddx * ddx + ddy * ddy);
        int conn = ((d > 0.0f) && (d < 10.0f)) || (i == j);
        float a = (sex[i] && sex[j] && conn) ? 1.0f : 0.0f;
        if (i == j) a += 1.0f;
        sA[l] = a;
    }
    __syncthreads();

    if (lt < N_) {
        float d = 0.0f;
        for (int j = 0; j < N_; ++j) d += sA[lt * N_ + j];
        snorm[lt] = (d > 0.0f) ? rsqrtf(d) : 0.0f;
    }
    __syncthreads();

    {
        float y = 0.0f;
        if (lt < 120) {
            int n = lt >> 1;
            int f = lt & 1;
            float s = 0.0f;
            for (int j = 0; j < N_; ++j) s += sA[n * N_ + j] * snorm[j] * sx[j * 2 + f];
            y = snorm[n] * s;
        }
        Y[(long)t * K2_ + lt] = f2bf(y);
    }
    __syncthreads();
}

__global__ void __launch_bounds__(256) spine_k(
    const unsigned short* Whh_bf, const unsigned short* Wih2_bf,
    const float* biasAll, float* c, unsigned short* hAll,
    const unsigned short* Yenc, unsigned short* Ydec,
    const unsigned short* W1_bf, const float* b1,
    const unsigned short* W2_bf, const float* b2,
    const unsigned short* W3_bf, const float* b3,
    const unsigned short* W4_bf, const float* b4,
    unsigned short* m1, unsigned short* m2, unsigned short* m3,
    float* out, const float* stdv, const float* meanv)
{
    cg::grid_group grid = cg::this_grid();
    __shared__ __align__(16) unsigned char smem[31744];
    int tid = threadIdx.x;
    int blk = blockIdx.x;

    // encoder spine: 5 steps (step 0 skips h-part: h == 0)
    for (int s = 0; s < 5; ++s) {
        whh_phase(smem, tid, blk, hAll + (long)s * HSLOT, Whh_bf,
                  Yenc + (long)s * 65536, Wih2_bf, biasAll, c,
                  hAll + (long)(s + 1) * HSLOT, s > 0);
        grid.sync();
    }

    // critical tail: MLP(4)->Y(5)->whh(5)->MLP(5)->Y(6)->whh(6)
    for (int s = 4; s <= 5; ++s) {
        const unsigned short* hs = hAll + (long)(s + 1) * HSLOT;
        mlp_phase(smem, tid, blk, 256, hs, W1_bf, b1, (float*)0, m1,
                  512, 512, 512, 2);
        grid.sync();
        mlp_phase(smem, tid, blk, 256, m1, W2_bf, b2, (float*)0, m2,
                  512, 1028, 512, 2);
        grid.sync();
        mlp_phase(smem, tid, blk, 256, m2, W3_bf, b3, (float*)0, m3,
                  512, 512, 1028, 2);
        grid.sync();
        mlp_phase(smem, tid, blk, 256, m3, W4_bf, b4,
                  out + (long)(s + 1) * PRED_SZ, (unsigned short*)0,
                  512, 120, 512, 3);
        grid.sync();
        gcn_phase(smem, tid, blk, out + (long)(s + 1) * PRED_SZ, stdv, meanv, Ydec);
        grid.sync();
        whh_phase(smem, tid, blk, hAll + (long)(s + 1) * HSLOT, Whh_bf,
                  Ydec, Wih2_bf, biasAll, c, hAll + (long)(s + 2) * HSLOT, 1);
        if (s == 4) grid.sync();
    }
}

extern "C" void kernel_launch(void* const* d_in, const int* in_sizes, int n_in,
                              void* d_out, int out_size, void* d_ws, size_t ws_size,
                              hipStream_t stream)
{
    const float* feat  = (const float*)d_in[0];
    const float* adjin = (const float*)d_in[1];
    const float* stdv  = (const float*)d_in[2];
    const float* meanv = (const float*)d_in[3];
    const float* gcnW  = (const float*)d_in[4];
    const float* gcnb  = (const float*)d_in[5];
    const float* Wih   = (const float*)d_in[6];
    const float* Whh   = (const float*)d_in[7];
    const float* bih   = (const float*)d_in[8];
    const float* bhh   = (const float*)d_in[9];
    const float* W1    = (const float*)d_in[10];
    const float* b1    = (const float*)d_in[11];
    const float* W2    = (const float*)d_in[12];
    const float* b2    = (const float*)d_in[13];
    const float* W3    = (const float*)d_in[14];
    const float* b3    = (const float*)d_in[15];
    const float* W4    = (const float*)d_in[16];
    const float* b4    = (const float*)d_in[17];
    float* out = (float*)d_out;

    // ws layout (~21.2 MB)
    float* c       = (float*)d_ws;                       // 262,144 f
    float* biasAll = c + 262144;                         // 2,048 f
    unsigned short* Y       = (unsigned short*)(biasAll + 2048);  // 6*65,536 us
    unsigned short* Ydec    = Y + 5 * 65536;             // decoder Y slot
    unsigned short* hAll    = Y + 6 * 65536;             // 8 * 262,144 us
    unsigned short* m1      = hAll + 8 * HSLOT;          // 1,310,720
    unsigned short* m2      = m1 + 1310720;              // 2,631,680
    unsigned short* m3      = m2 + 2631680;              // 1,310,720
    unsigned short* Whh_bf  = m3 + 1310720;              // 1,048,576
    unsigned short* W1_bf   = Whh_bf + 1048576;          // 262,144
    unsigned short* W2_bf   = W1_bf + 262144;            // 526,336
    unsigned short* W3_bf   = W2_bf + 526336;            // 526,336
    unsigned short* W4_bf   = W3_bf + 526336;            // 61,440
    unsigned short* Wih2_bf = W4_bf + 61440;             // 262,144

    prep_init_k<<<10496, 256, 0, stream>>>(Whh, W1, W2, W3, W4, feat,
                                           Whh_bf, W1_bf, W2_bf, W3_bf, W4_bf,
                                           hAll, c, out);
    wih2_k<<<FOURH, 256, 0, stream>>>(Wih, gcnW, gcnb, bih, bhh, Wih2_bf, biasAll);
    gcn_enc_y<<<5 * T_, 128, 0, stream>>>(feat, adjin, Y);

    // --- serial spine as ONE cooperative kernel (fallback: per-step launches)
    const unsigned short* Whh_c = Whh_bf;
    const unsigned short* Wih2_c = Wih2_bf;
    const float* biasAll_c = biasAll;
    const unsigned short* Yenc_c = Y;
    const unsigned short* W1c = W1_bf; const unsigned short* W2c = W2_bf;
    const unsigned short* W3c = W3_bf; const unsigned short* W4c = W4_bf;
    const float* b1c = b1; const float* b2c = b2;
    const float* b3c = b3; const float* b4c = b4;
    const float* stdc = stdv; const float* meanc = meanv;
    void* kargs[] = {
        (void*)&Whh_c, (void*)&Wih2_c, (void*)&biasAll_c, (void*)&c, (void*)&hAll,
        (void*)&Yenc_c, (void*)&Ydec,
        (void*)&W1c, (void*)&b1c, (void*)&W2c, (void*)&b2c,
        (void*)&W3c, (void*)&b3c, (void*)&W4c, (void*)&b4c,
        (void*)&m1, (void*)&m2, (void*)&m3,
        (void*)&out, (void*)&stdc, (void*)&meanc
    };
    hipError_t cerr = hipLaunchCooperativeKernel((const void*)spine_k,
                                                 dim3(256), dim3(256),
                                                 kargs, 0u, stream);
    if (cerr != hipSuccess) {
        // fallback: round-11 proven sequence of regular launches
        for (int s = 0; s < 5; ++s)
            whh_lstm_k<<<dim3(16, 16), 256, 0, stream>>>(hAll + (long)s * HSLOT,
                                                         Whh_bf, Y + (long)s * 65536,
                                                         Wih2_bf, biasAll, c,
                                                         hAll + (long)(s + 1) * HSLOT);
        for (int s = 4; s <= 5; ++s) {
            const unsigned short* hs = hAll + (long)(s + 1) * HSLOT;
            mlp_gemm<<<dim3(16, 16), 256, 0, stream>>>(hs, W1_bf, b1,
                                                       (float*)0, m1, T_, 512, 512, 2);
            mlp_gemm<<<dim3(33, 16), 256, 0, stream>>>(m1, W2_bf, b2,
                                                       (float*)0, m2, T_, 1028, 512, 2);
            mlp_gemm<<<dim3(16, 16), 256, 0, stream>>>(m2, W3_bf, b3,
                                                       (float*)0, m3, T_, 512, 1028, 2);
            mlp_gemm<<<dim3(4, 16), 256, 0, stream>>>(m3, W4_bf, b4,
                                                      out + (long)(s + 1) * PRED_SZ,
                                                      (unsigned short*)0, T_, 120, 512, 3);
            gcn_dec_y<<<T_, 128, 0, stream>>>(out + (long)(s + 1) * PRED_SZ,
                                              stdv, meanv, Ydec);
            whh_lstm_k<<<dim3(16, 16), 256, 0, stream>>>(hAll + (long)(s + 1) * HSLOT,
                                                         Whh_bf, Ydec, Wih2_bf, biasAll, c,
                                                         hAll + (long)(s + 2) * HSLOT);
        }
    }

    // --- batched MLP for off-critical-path steps {0,1,2,3,6}: M = 2560 ---
    mlp_w1b<<<dim3(16, 80), 256, 0, stream>>>(hAll, W1_bf, b1, m1);
    mlp_gemm<<<dim3(33, 80), 256, 0, stream>>>(m1, W2_bf, b2,
                                               (float*)0, m2, 2560, 1028, 512, 2);
    mlp_gemm<<<dim3(16, 80), 256, 0, stream>>>(m2, W3_bf, b3,
                                               (float*)0, m3, 2560, 512, 1028, 2);
    mlp_w4b<<<dim3(4, 80), 256, 0, stream>>>(m3, W4_bf, b4, out);
}

// Round 13
// 402.419 us; speedup vs baseline: 2.1194x; 2.1194x over previous
//
#include <hip/hip_runtime.h>

#define T_ 512
#define N_ 60
#define F_ 2
#define C_ 64
#define H_ 512
#define IN_ 3840
#define FOURH 2048
#define PRED_SZ 61440
#define ADJ_SZ 1843200
#define K2_ 128    // padded reduced-K for the Wih2 GEMM (120 real + 8 zero)
#define LDSK 40    // padded LDS row stride in bf16 units (2-way conflicts only)
#define HSLOT 262144   // one h slot (512*512 bf16)

typedef __attribute__((ext_vector_type(8))) short bf8;
typedef __attribute__((ext_vector_type(4))) float f4;

__device__ __forceinline__ unsigned short f2bf(float f)
{
    unsigned int u = __float_as_uint(f);
    u = (u + 0x7FFFu + ((u >> 16) & 1u)) >> 16;
    return (unsigned short)u;
}

// ===========================================================================
// Merged prep: weight casts + init (blocks 0..10495), Wih2+biasAll
// (blocks 10496..12543), encoder GCN 2-traj/block (blocks 12544..13823).
// All three parts are data-independent.
// ===========================================================================
__global__ __launch_bounds__(256) void prep_all_k(
    const float* Whh, const float* W1, const float* W2,
    const float* W3, const float* W4, const float* feat,
    const float* Wih, const float* gcnW, const float* gcnb,
    const float* bih, const float* bhh, const float* adj,
    unsigned short* Whh_bf, unsigned short* W1_bf, unsigned short* W2_bf,
    unsigned short* W3_bf, unsigned short* W4_bf,
    unsigned short* hAll, float* c, float* out,
    unsigned short* Wih2_bf, float* biasAll, unsigned short* Y)
{
    __shared__ __align__(16) unsigned char smem[30720];
    int bid = blockIdx.x;
    int tid = threadIdx.x;

    if (bid < 10496) {
        // ---- segment ladder: casts + init + frame-0 copy ----
        long i = (long)bid * 256 + tid;
        if (i < 1048576) { Whh_bf[i] = f2bf(Whh[i]); return; }
        i -= 1048576;
        if (i < 262144) { W1_bf[i] = f2bf(W1[i]); return; }
        i -= 262144;
        if (i < 526336) { W2_bf[i] = f2bf(W2[i]); return; }
        i -= 526336;
        if (i < 526336) { W3_bf[i] = f2bf(W3[i]); return; }
        i -= 526336;
        if (i < 61440) { W4_bf[i] = f2bf(W4[i]); return; }
        i -= 61440;
        hAll[i] = 0;
        c[i] = 0.0f;
        if (i < PRED_SZ) out[i] = feat[i];
        return;
    }

    if (bid < 12544) {
        // ---- Wih2 + biasAll (one o-row per block) ----
        int o = bid - 10496;
        float* row = (float*)smem;          // 3840
        float* wc  = row + IN_;             // 128
        float* bb  = wc + 128;              // 64
        float* red = bb + 64;               // 256

        if (tid < 128) wc[tid] = gcnW[tid];           // [2][64] row-major flat
        if (tid < 64) bb[tid] = gcnb[tid];
        for (int k = tid; k < IN_; k += 256) row[k] = Wih[(long)o * IN_ + k];
        __syncthreads();

        if (tid < 128) {
            float s = 0.0f;
            if (tid < 120) {
                int n = tid >> 1;
                int f = tid & 1;
                for (int c2 = 0; c2 < 64; ++c2) s += row[n * 64 + c2] * wc[f * 64 + c2];
            }
            Wih2_bf[(long)o * K2_ + tid] = f2bf(s);
        }

        float sb = 0.0f;
        for (int k = tid; k < IN_; k += 256) sb += row[k] * bb[k & 63];
        red[tid] = sb;
        __syncthreads();
        for (int s = 128; s > 0; s >>= 1) {
            if (tid < s) red[tid] += red[tid + s];
            __syncthreads();
        }
        if (tid == 0) biasAll[o] = bih[o] + bhh[o] + red[0];
        return;
    }

    // ---- encoder GCN, 2 trajectories per block ----
    {
        int gid = bid - 12544;            // 0..1279
        int half = tid >> 7;
        int lt = tid & 127;
        int tg = gid * 2 + half;          // 0..2559
        int frame = tg >> 9;
        int t = tg & 511;

        float* sA    = (float*)(smem + half * 15120);   // 3600 f
        float* sx    = sA + 3600;                        // 120 f (flat [n*2+f])
        float* snorm = sx + 120;                         // 60 f

        const float* xf = feat + (long)frame * PRED_SZ + (long)t * 120;
        const float* af = adj + (long)frame * ADJ_SZ + (long)t * 3600;

        for (int l = lt; l < N_ * N_; l += 128) {
            int i = l / N_;
            int j = l - i * N_;
            float a = af[l];
            if (i == j) a += 1.0f;
            sA[l] = a;
        }
        if (lt < 120) sx[lt] = xf[lt];
        __syncthreads();

        if (lt < N_) {
            float d = 0.0f;
            for (int j = 0; j < N_; ++j) d += sA[lt * N_ + j];
            snorm[lt] = (d > 0.0f) ? rsqrtf(d) : 0.0f;
        }
        __syncthreads();

        float y = 0.0f;
        if (lt < 120) {
            int n = lt >> 1;
            int f = lt & 1;
            float s = 0.0f;
            for (int j = 0; j < N_; ++j) s += sA[n * N_ + j] * snorm[j] * sx[j * 2 + f];
            y = snorm[n] * s;
        }
        Y[(long)tg * K2_ + lt] = f2bf(y);
    }
}

// ---------------------------------------------------------------------------
// Decoder GCN: radius graph from pred, then reduced Y. 512 blocks x 128 thr.
// ---------------------------------------------------------------------------
__global__ __launch_bounds__(128) void gcn_dec_y(
    const float* pred, const float* stdv, const float* meanv, unsigned short* Y)
{
    __shared__ float sA[N_][N_];
    __shared__ float sx[N_][2];
    __shared__ float dx0[N_];
    __shared__ float dx1[N_];
    __shared__ int sex[N_];
    __shared__ float snorm[N_];

    int t = blockIdx.x;
    int tid = threadIdx.x;
    const float* pr = pred + (long)t * 120;

    if (tid < 120) sx[tid >> 1][tid & 1] = pr[tid];
    if (tid < N_) {
        float vx = pr[tid * 2 + 0] * stdv[0] + meanv[0];
        float vy = pr[tid * 2 + 1] * stdv[1] + meanv[1];
        dx0[tid] = vx;
        dx1[tid] = vy;
        sex[tid] = (vx > 0.04f) && (vy > 0.04f);
    }
    __syncthreads();

    for (int l = tid; l < N_ * N_; l += 128) {
        int i = l / N_;
        int j = l - i * N_;
        float ddx = dx0[i] - dx0[j];
        float ddy = dx1[i] - dx1[j];
        float d = sqrtf(ddx * ddx + ddy * ddy);
        int conn = ((d > 0.0f) && (d < 10.0f)) || (i == j);
        float a = (sex[i] && sex[j] && conn) ? 1.0f : 0.0f;
        if (i == j) a += 1.0f;
        sA[i][j] = a;
    }
    __syncthreads();

    if (tid < N_) {
        float d = 0.0f;
        for (int j = 0; j < N_; ++j) d += sA[tid][j];
        snorm[tid] = (d > 0.0f) ? rsqrtf(d) : 0.0f;
    }
    __syncthreads();

    if (tid < 128) {
        float y = 0.0f;
        if (tid < 120) {
            int n = tid >> 1;
            int f = tid & 1;
            float s = 0.0f;
            for (int j = 0; j < N_; ++j) s += sA[n][j] * snorm[j] * sx[j][f];
            y = snorm[n] * s;
        }
        Y[(long)t * K2_ + tid] = f2bf(y);
    }
}

// ---------------------------------------------------------------------------
// 32x32-tile MFMA GEMM, B stored [K][Nc] (critical-tail MLP layers, M=512).
// Double-buffered LDS (one barrier per K-iter) + 2-deep register prefetch.
// mode 2: Cbf = bf16(relu(acc+b)); mode 3: Cf = acc+b.
// ---------------------------------------------------------------------------
__global__ __launch_bounds__(256) void mlp_gemm(
    const unsigned short* Abf, const unsigned short* Bb,
    const float* bias1, float* Cf, unsigned short* Cbf,
    int M, int Nc, int K, int mode)
{
    __shared__ unsigned short As[2][32 * LDSK];
    __shared__ unsigned short Bs[2][32 * LDSK];

    int tid = threadIdx.x;
    int wave = tid >> 6;
    int wt = wave >> 1, wj = wave & 1;
    int lane = tid & 63;
    int quad = lane >> 4;
    int l16 = lane & 15;
    int row0 = blockIdx.y * 32;
    int col0 = blockIdx.x * 32;

    f4 acc = {0.f, 0.f, 0.f, 0.f};
    const ushort4 zu = make_ushort4(0, 0, 0, 0);
    int sr = tid >> 3;
    int sko = (tid & 7) * 4;

    auto loadA = [&](int k0, ushort4& v) {
        int gm = row0 + sr, gk = k0 + sko;
        v = zu;
        if (gm < M && gk + 4 <= K) v = *(const ushort4*)&Abf[(long)gm * K + gk];
    };
    auto loadB = [&](int k0, ushort4& v) {
        int gk = k0 + sr;
        int gn0 = col0 + sko;
        v = zu;
        if (gk < K) {
            if (gn0 + 4 <= Nc) {
                v = *(const ushort4*)&Bb[(long)gk * Nc + gn0];
            } else {
                unsigned short tmp[4] = {0, 0, 0, 0};
                for (int i = 0; i < 4; ++i)
                    if (gn0 + i < Nc) tmp[i] = Bb[(long)gk * Nc + gn0 + i];
                v = make_ushort4(tmp[0], tmp[1], tmp[2], tmp[3]);
            }
        }
    };

    int niter = (K + 31) / 32;
    ushort4 a0, b0, a1 = zu, b1 = zu, a2 = zu, b2 = zu;
    loadA(0, a0);
    loadB(0, b0);
    if (niter > 1) { loadA(32, a1); loadB(32, b1); }

    for (int it = 0; it < niter; ++it) {
        if (it + 2 < niter) {
            loadA((it + 2) * 32, a2);
            loadB((it + 2) * 32, b2);
        }
        int bf = it & 1;
        *(ushort4*)&As[bf][sr * LDSK + sko] = a0;
        Bs[bf][(sko + 0) * LDSK + sr] = b0.x;
        Bs[bf][(sko + 1) * LDSK + sr] = b0.y;
        Bs[bf][(sko + 2) * LDSK + sr] = b0.z;
        Bs[bf][(sko + 3) * LDSK + sr] = b0.w;
        __syncthreads();

        bf8 fa = *(const bf8*)&As[bf][(wt * 16 + l16) * LDSK + quad * 8];
        bf8 fb = *(const bf8*)&Bs[bf][(wj * 16 + l16) * LDSK + quad * 8];
        acc = __builtin_amdgcn_mfma_f32_16x16x32_bf16(fa, fb, acc, 0, 0, 0);

        a0 = a1; a1 = a2; b0 = b1; b1 = b2;
    }

    int gn = col0 + wj * 16 + l16;
    if (gn < Nc) {
        float bsv = bias1[gn];
        #pragma unroll
        for (int r = 0; r < 4; ++r) {
            int gm = row0 + wt * 16 + quad * 4 + r;
            if (gm >= M) continue;
            float v = acc[r] + bsv;
            long idx = (long)gm * Nc + gn;
            if (mode == 2) {
                if (v < 0.0f) v = 0.0f;
                Cbf[idx] = f2bf(v);
            } else {
                Cf[idx] = v;
            }
        }
    }
}

// ---------------------------------------------------------------------------
// 64x64-tile GEMM for the batched MLP (M=2560): 4 waves, 2x2 MFMA each.
// B stored [K][Nc]; output bf16 relu. indirect=1: A rows map through hAll
// slots {1,2,3,4,7} (row gr -> slot gr>>9). dbuf LDS + 2-deep prefetch.
// ---------------------------------------------------------------------------
__global__ __launch_bounds__(256) void b64_k(
    const unsigned short* Abf, const unsigned short* hAll, int indirect,
    const unsigned short* Bb, const float* bias1, unsigned short* Cbf,
    int M, int Nc, int K)
{
    __shared__ unsigned short As[2][64 * LDSK];
    __shared__ unsigned short Bs[2][64 * LDSK];

    int tid = threadIdx.x;
    int wave = tid >> 6;
    int lane = tid & 63;
    int quad = lane >> 4;
    int l16 = lane & 15;
    int wr = (wave >> 1) * 32;
    int wc = (wave & 1) * 32;
    int row0 = blockIdx.y * 64;
    int col0 = blockIdx.x * 64;

    f4 acc00 = {0.f,0.f,0.f,0.f}, acc01 = {0.f,0.f,0.f,0.f};
    f4 acc10 = {0.f,0.f,0.f,0.f}, acc11 = {0.f,0.f,0.f,0.f};
    const ushort4 zu = make_ushort4(0, 0, 0, 0);

    int ar = tid >> 2;             // 0..63
    int ako = (tid & 3) * 8;       // 0,8,16,24
    int bkk = tid >> 3;            // 0..31
    int bnp = (tid & 7) * 8;       // 0..56

    int gr = row0 + ar;
    const unsigned short* arow;
    if (indirect) {
        int sidx = gr >> 9;
        int slot = (sidx < 4) ? (sidx + 1) : 7;
        arow = hAll + (long)slot * HSLOT + (long)(gr & 511) * K;
    } else {
        arow = Abf + (long)gr * K;
    }

    auto loadA = [&](int k0, ushort4& v0, ushort4& v1) {
        int gk = k0 + ako;
        v0 = zu; v1 = zu;
        if (gk + 4 <= K) v0 = *(const ushort4*)&arow[gk];
        if (gk + 8 <= K) v1 = *(const ushort4*)&arow[gk + 4];
    };
    auto loadB = [&](int k0, ushort4& v0, ushort4& v1) {
        int gk = k0 + bkk;
        int gn0 = col0 + bnp;
        v0 = zu; v1 = zu;
        if (gk < K) {
            if (gn0 + 4 <= Nc) {
                v0 = *(const ushort4*)&Bb[(long)gk * Nc + gn0];
            } else {
                unsigned short t0[4] = {0,0,0,0};
                for (int i = 0; i < 4; ++i)
                    if (gn0 + i < Nc) t0[i] = Bb[(long)gk * Nc + gn0 + i];
                v0 = make_ushort4(t0[0], t0[1], t0[2], t0[3]);
            }
            if (gn0 + 8 <= Nc) {
                v1 = *(const ushort4*)&Bb[(long)gk * Nc + gn0 + 4];
            } else {
                unsigned short t1[4] = {0,0,0,0};
                for (int i = 0; i < 4; ++i)
                    if (gn0 + 4 + i < Nc) t1[i] = Bb[(long)gk * Nc + gn0 + 4 + i];
                v1 = make_ushort4(t1[0], t1[1], t1[2], t1[3]);
            }
        }
    };

    int niter = (K + 31) / 32;
    ushort4 a00, a01, b00, b01;
    ushort4 a10 = zu, a11 = zu, b10 = zu, b11 = zu;
    ushort4 a20 = zu, a21 = zu, b20 = zu, b21 = zu;
    loadA(0, a00, a01);
    loadB(0, b00, b01);
    if (niter > 1) { loadA(32, a10, a11); loadB(32, b10, b11); }

    for (int it = 0; it < niter; ++it) {
        if (it + 2 < niter) {
            loadA((it + 2) * 32, a20, a21);
            loadB((it + 2) * 32, b20, b21);
        }
        int bf = it & 1;
        *(ushort4*)&As[bf][ar * LDSK + ako]     = a00;
        *(ushort4*)&As[bf][ar * LDSK + ako + 4] = a01;
        Bs[bf][(bnp + 0) * LDSK + bkk] = b00.x;
        Bs[bf][(bnp + 1) * LDSK + bkk] = b00.y;
        Bs[bf][(bnp + 2) * LDSK + bkk] = b00.z;
        Bs[bf][(bnp + 3) * LDSK + bkk] = b00.w;
        Bs[bf][(bnp + 4) * LDSK + bkk] = b01.x;
        Bs[bf][(bnp + 5) * LDSK + bkk] = b01.y;
        Bs[bf][(bnp + 6) * LDSK + bkk] = b01.z;
        Bs[bf][(bnp + 7) * LDSK + bkk] = b01.w;
        __syncthreads();

        bf8 fa0 = *(const bf8*)&As[bf][(wr + l16) * LDSK + quad * 8];
        bf8 fa1 = *(const bf8*)&As[bf][(wr + 16 + l16) * LDSK + quad * 8];
        bf8 fb0 = *(const bf8*)&Bs[bf][(wc + l16) * LDSK + quad * 8];
        bf8 fb1 = *(const bf8*)&Bs[bf][(wc + 16 + l16) * LDSK + quad * 8];

        acc00 = __builtin_amdgcn_mfma_f32_16x16x32_bf16(fa0, fb0, acc00, 0, 0, 0);
        acc01 = __builtin_amdgcn_mfma_f32_16x16x32_bf16(fa0, fb1, acc01, 0, 0, 0);
        acc10 = __builtin_amdgcn_mfma_f32_16x16x32_bf16(fa1, fb0, acc10, 0, 0, 0);
        acc11 = __builtin_amdgcn_mfma_f32_16x16x32_bf16(fa1, fb1, acc11, 0, 0, 0);
        __syncthreads();

        a00 = a10; a01 = a11; a10 = a20; a11 = a21;
        b00 = b10; b01 = b11; b10 = b20; b11 = b21;
    }

    #pragma unroll
    for (int mi = 0; mi < 2; ++mi) {
        #pragma unroll
        for (int ni = 0; ni < 2; ++ni) {
            int gn = col0 + wc + ni * 16 + l16;
            if (gn >= Nc) continue;
            float bsv = bias1[gn];
            #pragma unroll
            for (int r = 0; r < 4; ++r) {
                int gm = row0 + wr + mi * 16 + quad * 4 + r;
                float v;
                if (mi == 0 && ni == 0) v = acc00[r];
                else if (mi == 0)       v = acc01[r];
                else if (ni == 0)       v = acc10[r];
                else                    v = acc11[r];
                v += bsv;
                if (v < 0.0f) v = 0.0f;
                Cbf[(long)gm * Nc + gn] = f2bf(v);
            }
        }
    }
}

// ---------------------------------------------------------------------------
// Batched W4 (32-tile): A = m3 (2560 x 512), Nc=120; rows -> frames {1,2,3,4,7}
// ---------------------------------------------------------------------------
__global__ __launch_bounds__(256) void mlp_w4b(
    const unsigned short* Abf, const unsigned short* Bb,
    const float* bias1, float* out)
{
    __shared__ unsigned short As[2][32 * LDSK];
    __shared__ unsigned short Bs[2][32 * LDSK];

    int tid = threadIdx.x;
    int wave = tid >> 6;
    int wt = wave >> 1, wj = wave & 1;
    int lane = tid & 63;
    int quad = lane >> 4;
    int l16 = lane & 15;
    int row0 = blockIdx.y * 32;
    int col0 = blockIdx.x * 32;

    f4 acc = {0.f, 0.f, 0.f, 0.f};
    const ushort4 zu = make_ushort4(0, 0, 0, 0);
    int sr = tid >> 3;
    int sko = (tid & 7) * 4;

    auto loadA = [&](int k0, ushort4& v) {
        v = *(const ushort4*)&Abf[(long)(row0 + sr) * 512 + k0 + sko];
    };
    auto loadB = [&](int k0, ushort4& v) {
        int gn0 = col0 + sko;
        v = zu;
        if (gn0 + 4 <= 120) {
            v = *(const ushort4*)&Bb[(long)(k0 + sr) * 120 + gn0];
        } else {
            unsigned short tmp[4] = {0, 0, 0, 0};
            for (int i = 0; i < 4; ++i)
                if (gn0 + i < 120) tmp[i] = Bb[(long)(k0 + sr) * 120 + gn0 + i];
            v = make_ushort4(tmp[0], tmp[1], tmp[2], tmp[3]);
        }
    };

    ushort4 a0, b0, a1, b1, a2 = zu, b2 = zu;
    loadA(0, a0); loadB(0, b0);
    loadA(32, a1); loadB(32, b1);

    for (int it = 0; it < 16; ++it) {
        if (it + 2 < 16) { loadA((it + 2) * 32, a2); loadB((it + 2) * 32, b2); }
        int bf = it & 1;
        *(ushort4*)&As[bf][sr * LDSK + sko] = a0;
        Bs[bf][(sko + 0) * LDSK + sr] = b0.x;
        Bs[bf][(sko + 1) * LDSK + sr] = b0.y;
        Bs[bf][(sko + 2) * LDSK + sr] = b0.z;
        Bs[bf][(sko + 3) * LDSK + sr] = b0.w;
        __syncthreads();

        bf8 fa = *(const bf8*)&As[bf][(wt * 16 + l16) * LDSK + quad * 8];
        bf8 fb = *(const bf8*)&Bs[bf][(wj * 16 + l16) * LDSK + quad * 8];
        acc = __builtin_amdgcn_mfma_f32_16x16x32_bf16(fa, fb, acc, 0, 0, 0);

        a0 = a1; a1 = a2; b0 = b1; b1 = b2;
    }

    int gn = col0 + wj * 16 + l16;
    if (gn < 120) {
        float bsv = bias1[gn];
        #pragma unroll
        for (int r = 0; r < 4; ++r) {
            int gm = row0 + wt * 16 + quad * 4 + r;
            int sidx = gm >> 9;
            int frame = (sidx < 4) ? (sidx + 1) : 7;
            out[(long)frame * PRED_SZ + (long)(gm & 511) * 120 + gn] = acc[r] + bsv;
        }
    }
}

// ---------------------------------------------------------------------------
// Fused gates + LSTM, high-occupancy: block tile 16t x 32j x 4 gates,
// grid (16 j, 32 t) = 512 blocks (2 blocks/CU). Wave g computes gate g
// (2 MFMA/iter); epilogue exchanges gates via LDS. K = 4 Y-iters + 16 h-iters
// (withH=0 -> only Y-iters; h==0 so skipped MFMAs add exact zeros).
// ---------------------------------------------------------------------------
__global__ __launch_bounds__(256) void whh_lstm2_k(
    const unsigned short* hprev, const unsigned short* Whh_bf,
    const unsigned short* Yf, const unsigned short* Wih2_bf,
    const float* biasAll, float* c, unsigned short* hnew, int withH)
{
    __shared__ __align__(16) union {
        struct {
            unsigned short A[2][16 * LDSK];    // 2,560 B
            unsigned short B[2][128 * LDSK];   // 20,480 B
        } s;
        float g[4][16][32];                    // 8,192 B (epilogue exchange)
    } sm;

    int tid = threadIdx.x;
    int g = tid >> 6;                 // wave = gate
    int lane = tid & 63;
    int quad = lane >> 4;
    int l16 = lane & 15;
    int j0 = blockIdx.x * 32;
    int row0 = blockIdx.y * 16;

    // A staging: threads 0..127, one ushort4 each (16 rows x 32 k)
    int asr = tid >> 3;               // 0..31 (only <16 used via tid<128)
    int ako = (tid & 7) * 4;
    // B staging: all 256 threads, two uint4 each (128 rows x 32 k)
    int br = tid >> 1;                // 0..127 (gate = br>>5, jj = br&31)
    int bko = (tid & 1) * 16;
    long brow = (long)((br >> 5) * H_ + j0 + (br & 31));
    long bb_w = brow * H_;
    long bb_y = brow * K2_;
    long ar_h = (long)(row0 + asr) * H_;
    long ar_y = (long)(row0 + asr) * K2_;

    f4 acc[2];
    acc[0] = f4{0.f, 0.f, 0.f, 0.f};
    acc[1] = f4{0.f, 0.f, 0.f, 0.f};

    int niter = withH ? 20 : 4;

    auto loadT = [&](int it, ushort4& a, uint4& q0, uint4& q1) {
        if (it < 4) {
            int k = it * 32;
            if (tid < 128) a = *(const ushort4*)&Yf[ar_y + k + ako];
            q0 = *(const uint4*)&Wih2_bf[bb_y + k + bko];
            q1 = *(const uint4*)&Wih2_bf[bb_y + k + bko + 8];
        } else {
            int k = (it - 4) * 32;
            if (tid < 128) a = *(const ushort4*)&hprev[ar_h + k + ako];
            q0 = *(const uint4*)&Whh_bf[bb_w + k + bko];
            q1 = *(const uint4*)&Whh_bf[bb_w + k + bko + 8];
        }
    };

    ushort4 a0 = make_ushort4(0,0,0,0), a1 = a0, a2 = a0;
    uint4 q00, q01, q10, q11, q20 = uint4{0,0,0,0}, q21 = uint4{0,0,0,0};
    loadT(0, a0, q00, q01);
    loadT(1, a1, q10, q11);

    for (int it = 0; it < niter; ++it) {
        if (it + 2 < niter) loadT(it + 2, a2, q20, q21);
        int bf = it & 1;
        if (tid < 128) *(ushort4*)&sm.s.A[bf][asr * LDSK + ako] = a0;
        *(uint4*)&sm.s.B[bf][br * LDSK + bko]     = q00;
        *(uint4*)&sm.s.B[bf][br * LDSK + bko + 8] = q01;
        __syncthreads();

        bf8 fa = *(const bf8*)&sm.s.A[bf][l16 * LDSK + quad * 8];
        #pragma unroll
        for (int jh = 0; jh < 2; ++jh) {
            bf8 fb = *(const bf8*)&sm.s.B[bf][(g * 32 + jh * 16 + l16) * LDSK + quad * 8];
            acc[jh] = __builtin_amdgcn_mfma_f32_16x16x32_bf16(fa, fb, acc[jh], 0, 0, 0);
        }

        a0 = a1; a1 = a2;
        q00 = q10; q01 = q11; q10 = q20; q11 = q21;
    }

    // exchange gates via LDS: thread holds gate g, rows quad*4+r, cols jh*16+l16
    __syncthreads();
    #pragma unroll
    for (int jh = 0; jh < 2; ++jh)
        #pragma unroll
        for (int r = 0; r < 4; ++r)
            sm.g[g][quad * 4 + r][jh * 16 + l16] = acc[jh][r];
    __syncthreads();

    // LSTM pointwise: 512 cells, 2 per thread
    for (int cell = tid; cell < 512; cell += 256) {
        int tloc = cell >> 5;
        int j = cell & 31;
        int t = row0 + tloc;
        int jg = j0 + j;
        float gi = sm.g[0][tloc][j] + biasAll[jg];
        float gf = sm.g[1][tloc][j] + biasAll[512 + jg];
        float gg = sm.g[2][tloc][j] + biasAll[1024 + jg];
        float go = sm.g[3][tloc][j] + biasAll[1536 + jg];
        float ig = 1.0f / (1.0f + expf(-gi));
        float fg = 1.0f / (1.0f + expf(-gf));
        float g2 = tanhf(gg);
        float og = 1.0f / (1.0f + expf(-go));
        long ci = (long)t * H_ + jg;
        float cn = fg * c[ci] + ig * g2;
        c[ci] = cn;
        hnew[ci] = f2bf(og * tanhf(cn));
    }
}

extern "C" void kernel_launch(void* const* d_in, const int* in_sizes, int n_in,
                              void* d_out, int out_size, void* d_ws, size_t ws_size,
                              hipStream_t stream)
{
    const float* feat  = (const float*)d_in[0];
    const float* adjin = (const float*)d_in[1];
    const float* stdv  = (const float*)d_in[2];
    const float* meanv = (const float*)d_in[3];
    const float* gcnW  = (const float*)d_in[4];
    const float* gcnb  = (const float*)d_in[5];
    const float* Wih   = (const float*)d_in[6];
    const float* Whh   = (const float*)d_in[7];
    const float* bih   = (const float*)d_in[8];
    const float* bhh   = (const float*)d_in[9];
    const float* W1    = (const float*)d_in[10];
    const float* b1    = (const float*)d_in[11];
    const float* W2    = (const float*)d_in[12];
    const float* b2    = (const float*)d_in[13];
    const float* W3    = (const float*)d_in[14];
    const float* b3    = (const float*)d_in[15];
    const float* W4    = (const float*)d_in[16];
    const float* b4    = (const float*)d_in[17];
    float* out = (float*)d_out;

    // ws layout (~21.2 MB)
    float* c       = (float*)d_ws;                       // 262,144 f
    float* biasAll = c + 262144;                         // 2,048 f
    unsigned short* Y       = (unsigned short*)(biasAll + 2048);  // 6*65,536 us
    unsigned short* Ydec    = Y + 5 * 65536;             // decoder Y slot
    unsigned short* hAll    = Y + 6 * 65536;             // 8 * 262,144 us
    unsigned short* m1      = hAll + 8 * HSLOT;          // 1,310,720
    unsigned short* m2      = m1 + 1310720;              // 2,631,680
    unsigned short* m3      = m2 + 2631680;              // 1,310,720
    unsigned short* Whh_bf  = m3 + 1310720;              // 1,048,576
    unsigned short* W1_bf   = Whh_bf + 1048576;          // 262,144
    unsigned short* W2_bf   = W1_bf + 262144;            // 526,336
    unsigned short* W3_bf   = W2_bf + 526336;            // 526,336
    unsigned short* W4_bf   = W3_bf + 526336;            // 61,440
    unsigned short* Wih2_bf = W4_bf + 61440;             // 262,144

    // one merged prep launch: casts+init | Wih2+bias | encoder GCN
    prep_all_k<<<13824, 256, 0, stream>>>(Whh, W1, W2, W3, W4, feat,
                                          Wih, gcnW, gcnb, bih, bhh, adjin,
                                          Whh_bf, W1_bf, W2_bf, W3_bf, W4_bf,
                                          hAll, c, out, Wih2_bf, biasAll, Y);

    // encoder spine: 5 sequential fused gates+LSTM steps
    for (int s = 0; s < 5; ++s)
        whh_lstm2_k<<<dim3(16, 32), 256, 0, stream>>>(hAll + (long)s * HSLOT,
                                                      Whh_bf, Y + (long)s * 65536,
                                                      Wih2_bf, biasAll, c,
                                                      hAll + (long)(s + 1) * HSLOT,
                                                      s > 0);

    // critical tail: MLP(4)->Y(5)->whh(5)->MLP(5)->Y(6)->whh(6)
    for (int s = 4; s <= 5; ++s) {
        const unsigned short* hs = hAll + (long)(s + 1) * HSLOT;
        mlp_gemm<<<dim3(16, 16), 256, 0, stream>>>(hs, W1_bf, b1,
                                                   (float*)0, m1, T_, 512, 512, 2);
        mlp_gemm<<<dim3(33, 16), 256, 0, stream>>>(m1, W2_bf, b2,
                                                   (float*)0, m2, T_, 1028, 512, 2);
        mlp_gemm<<<dim3(16, 16), 256, 0, stream>>>(m2, W3_bf, b3,
                                                   (float*)0, m3, T_, 512, 1028, 2);
        mlp_gemm<<<dim3(4, 16), 256, 0, stream>>>(m3, W4_bf, b4,
                                                  out + (long)(s + 1) * PRED_SZ,
                                                  (unsigned short*)0, T_, 120, 512, 3);
        gcn_dec_y<<<T_, 128, 0, stream>>>(out + (long)(s + 1) * PRED_SZ,
                                          stdv, meanv, Ydec);
        whh_lstm2_k<<<dim3(16, 32), 256, 0, stream>>>(hAll + (long)(s + 1) * HSLOT,
                                                      Whh_bf, Ydec, Wih2_bf, biasAll, c,
                                                      hAll + (long)(s + 2) * HSLOT, 1);
    }

    // batched MLP for off-critical-path steps {0,1,2,3,6}: M = 2560 (64-tile)
    b64_k<<<dim3(8, 40), 256, 0, stream>>>((const unsigned short*)0, hAll, 1,
                                           W1_bf, b1, m1, 2560, 512, 512);
    b64_k<<<dim3(17, 40), 256, 0, stream>>>(m1, (const unsigned short*)0, 0,
                                            W2_bf, b2, m2, 2560, 1028, 512);
    b64_k<<<dim3(8, 40), 256, 0, stream>>>(m2, (const unsigned short*)0, 0,
                                           W3_bf, b3, m3, 2560, 512, 1028);
    mlp_w4b<<<dim3(4, 80), 256, 0, stream>>>(m3, W4_bf, b4, out);
}